// Round 1
// 274.403 us; speedup vs baseline: 1.0252x; 1.0252x over previous
//
#include <hip/hip_runtime.h>
#include <math.h>

// Problem constants
#define NN 32768
#define CC 512
#define AA 64
#define CIN 1024
#define EPSV 1e-7f

// All inputs/outputs are FLOAT32 (reference dtype).
//
// Workspace layout (floats) — every region is fully written each launch
// (poison-safe, no memset needed):
//   [0,12800)      dotp[8][1600]  per-chunk row-dot partials (chunk-major):
//                  rows [0,576) Wq, [576,1088) Wer, [1088,1600) Wch
//   [12800,12824)  sdot[3][8]     scalar-dot partials (ush,ulr,uca)
//   [12824,13336)  contx[512]     W_content_input @ x (direct store)
//   [13344,14880)  stats[1536]:   m_b[512], Zl[512], S2l[512]
//   [14912,47680)  pa[64][512]    A-col partials (col-major: j*512+b)
//   [47680,571968) pm[1024][512]  M-col partials: e*512+b
//                  (e<512 -> w*M, e>=512 -> w^2*M)

#define DOTP  0
#define SDOT  12800
#define CONTX 12824
#define STOFF 13344
#define PAOFF 14912
#define PMOFF 47680

typedef float floatx4 __attribute__((ext_vector_type(4)));

__device__ __forceinline__ float4 ntload4(const float4* p) {
    floatx4 v = __builtin_nontemporal_load(reinterpret_cast<const floatx4*>(p));
    return make_float4(v.x, v.y, v.z, v.w);
}
__device__ __forceinline__ float ntloadf(const float* p) {
    return __builtin_nontemporal_load(p);
}

// ---------------- K1: all GEMVs + scalar dots, row-blocked ----------------
// grid 1688 blocks x 256 thr:
//   b<1600 : big GEMV (rows [0,1600) over Wq/Wer/Wch). rg=b>>3 (8 rows),
//            chunk=b&7 (4096 cols). h chunk staged in LDS, shared by 8 rows.
//            Register double-buffer across the 4 col-iterations; nt loads.
//            Stores per-chunk partial -> dotp[chunk][row] (no atomics).
//   b<1664 : Wci rows (8 per block, full 1024 cols) -> direct store.
//   b<1688 : 3 scalar dots x 8 chunks -> sdot[sd][chunk].
__global__ __launch_bounds__(256) void k1_gemv(
    const float* __restrict__ h, const float* __restrict__ x,
    const float* __restrict__ Wq, const float* __restrict__ Wer,
    const float* __restrict__ Wch, const float* __restrict__ Wci,
    const float* __restrict__ ush, const float* __restrict__ ulr,
    const float* __restrict__ uca, float* __restrict__ ws)
{
    const int b = blockIdx.x, tid = threadIdx.x;
    const int wave = tid >> 6, lane = tid & 63;
    __shared__ float hs[4096];
    __shared__ float red[4][8];

    if (b < 1600) {
        const int rg = b >> 3, chunk = b & 7;
        const float4* h4 = reinterpret_cast<const float4*>(h) + chunk * 1024;
        float4* hs4 = reinterpret_cast<float4*>(hs);
        #pragma unroll
        for (int k = 0; k < 4; ++k) hs4[k * 256 + tid] = h4[k * 256 + tid];
        __syncthreads();
        const int r0 = rg * 8;
        const float* mat; int base;
        if (r0 < 576)       { mat = Wq;  base = 0; }
        else if (r0 < 1088) { mat = Wer; base = 576; }
        else                { mat = Wch; base = 1088; }
        const float4* m4 = reinterpret_cast<const float4*>(
            mat + (size_t)(r0 - base) * NN + chunk * 4096);
        const int rs = NN / 4; // row stride in float4
        float acc[8] = {0,0,0,0,0,0,0,0};
        float4 cur[8];
        #pragma unroll
        for (int r = 0; r < 8; ++r) cur[r] = ntload4(m4 + (size_t)r * rs + tid);
        #pragma unroll
        for (int it = 0; it < 4; ++it) {
            float4 nxt[8];
            if (it < 3) {
                #pragma unroll
                for (int r = 0; r < 8; ++r)
                    nxt[r] = ntload4(m4 + (size_t)r * rs + (it + 1) * 256 + tid);
            }
            float4 hb = hs4[it * 256 + tid];
            #pragma unroll
            for (int r = 0; r < 8; ++r)
                acc[r] += cur[r].x * hb.x + cur[r].y * hb.y +
                          cur[r].z * hb.z + cur[r].w * hb.w;
            if (it < 3) {
                #pragma unroll
                for (int r = 0; r < 8; ++r) cur[r] = nxt[r];
            }
        }
        #pragma unroll
        for (int r = 0; r < 8; ++r) {
            #pragma unroll
            for (int off = 32; off >= 1; off >>= 1)
                acc[r] += __shfl_xor(acc[r], off);
        }
        if (lane == 0) {
            #pragma unroll
            for (int r = 0; r < 8; ++r) red[wave][r] = acc[r];
        }
        __syncthreads();
        if (tid < 8) {
            float v = red[0][tid] + red[1][tid] + red[2][tid] + red[3][tid];
            ws[DOTP + chunk * 1600 + r0 + tid] = v;
        }
    } else if (b < 1664) {
        const int rg = b - 1600; // 8 rows of Wci each
        float4 xv = reinterpret_cast<const float4*>(x)[tid];
        const float4* m4 = reinterpret_cast<const float4*>(
            Wci + (size_t)rg * 8 * CIN);
        float acc[8];
        #pragma unroll
        for (int r = 0; r < 8; ++r) {
            float4 a = ntload4(m4 + r * 256 + tid);
            acc[r] = a.x * xv.x + a.y * xv.y + a.z * xv.z + a.w * xv.w;
        }
        #pragma unroll
        for (int r = 0; r < 8; ++r) {
            #pragma unroll
            for (int off = 32; off >= 1; off >>= 1)
                acc[r] += __shfl_xor(acc[r], off);
        }
        if (lane == 0) {
            #pragma unroll
            for (int r = 0; r < 8; ++r) red[wave][r] = acc[r];
        }
        __syncthreads();
        if (tid < 8) {
            float v = red[0][tid] + red[1][tid] + red[2][tid] + red[3][tid];
            ws[CONTX + rg * 8 + tid] = v;
        }
    } else {
        const int t = b - 1664, sd = t >> 3, chunk = t & 7;
        const float* vec = (sd == 0) ? ush : (sd == 1) ? ulr : uca;
        const float4* v4 = reinterpret_cast<const float4*>(vec) + chunk * 1024;
        const float4* h4 = reinterpret_cast<const float4*>(h) + chunk * 1024;
        float acc = 0.f;
        #pragma unroll
        for (int it = 0; it < 4; ++it) {
            float4 a = v4[it * 256 + tid];
            float4 hb = h4[it * 256 + tid];
            acc += a.x * hb.x + a.y * hb.y + a.z * hb.z + a.w * hb.w;
        }
        if (sd == 2 && chunk == 0) { // x-tail of u_content_alpha
            float4 a = reinterpret_cast<const float4*>(uca)[NN / 4 + tid];
            float4 xv = reinterpret_cast<const float4*>(x)[tid];
            acc += a.x * xv.x + a.y * xv.y + a.z * xv.z + a.w * xv.w;
        }
        #pragma unroll
        for (int off = 32; off >= 1; off >>= 1)
            acc += __shfl_xor(acc, off);
        if (lane == 0) red[wave][0] = acc;
        __syncthreads();
        if (tid == 0)
            ws[SDOT + sd * 8 + chunk] =
                red[0][0] + red[1][0] + red[2][0] + red[3][0];
    }
}

// ---------------- K2f: fused scalars + sim + online-softmax + accumulation
// grid 512 x 512 (8 waves). Prologue: rebuild q (=dot partials + bias) in
// LDS, block-reduce qnorm, fold in beta/gamma nonlinearities (absorbs old
// k1b). Then block b handles rows [b*64, b*64+64); wave w handles 8 rows.
// Single pass over M+A with online-softmax accumulation; block merge in LDS
// with per-wave scale factors; emit per-block partials + (m_b, Zl, S2l).
__global__ __launch_bounds__(512) void k2f_fused(
    const float* __restrict__ Mm, const float* __restrict__ Ad,
    const float* __restrict__ ema, const float* __restrict__ ws,
    const float* __restrict__ bq, const float* __restrict__ bsh,
    const float* __restrict__ blr,
    float* __restrict__ pm, float* __restrict__ pa, float* __restrict__ stats)
{
    __shared__ float lw[8][1092];
    __shared__ __align__(16) float qsh[576];
    __shared__ float r2[12];
    const int b = blockIdx.x, tid = threadIdx.x, wave = tid >> 6, lane = tid & 63;

    // ---- prologue: q, qnorm, beta, gamma (was k1b) ----
    float qq = 0.f;
    for (int j = tid; j < 576; j += 512) {
        float s = bq[j];
        #pragma unroll
        for (int c = 0; c < 8; ++c) s += ws[DOTP + c * 1600 + j];
        qsh[j] = s;
        qq += s * s;
    }
    #pragma unroll
    for (int off = 32; off >= 1; off >>= 1) qq += __shfl_xor(qq, off);
    if (lane == 0) r2[wave] = qq;
    __syncthreads();
    if (tid == 0) {
        float qn2 = 0.f;
        #pragma unroll
        for (int w = 0; w < 8; ++w) qn2 += r2[w];
        float bp = bsh[0], gp = blr[0];
        #pragma unroll
        for (int c = 0; c < 8; ++c) { bp += ws[SDOT + c]; gp += ws[SDOT + 8 + c]; }
        r2[8]  = fmaxf(sqrtf(qn2), EPSV);
        r2[9]  = (bp > 20.f ? bp : log1pf(expf(bp))) + 1.0f; // softplus+1
        r2[10] = 1.f / (1.f + expf(-gp));                    // sigmoid
    }
    __syncthreads();
    const float qn = r2[8], beta = r2[9], gamma = r2[10];
    const float ql = qsh[lane];
    float4 qa = *reinterpret_cast<const float4*>(qsh + 64 + lane * 8);
    float4 qb = *reinterpret_cast<const float4*>(qsh + 68 + lane * 8);
    float qm[8] = {qa.x, qa.y, qa.z, qa.w, qb.x, qb.y, qb.z, qb.w};

    float a1[8] = {0,0,0,0,0,0,0,0};
    float a2[8] = {0,0,0,0,0,0,0,0};
    float aA = 0.f, m_run = -1e30f, Z = 0.f, S2 = 0.f;
    const int base = b * 64 + wave * 8;
    for (int j = 0; j < 8; ++j) {
        const int i = base + j;
        float a = ntloadf(Ad + (size_t)i * AA + lane);
        float4 m0 = ntload4(reinterpret_cast<const float4*>(Mm + (size_t)i * CC + lane * 8));
        float4 m1 = ntload4(reinterpret_cast<const float4*>(Mm + (size_t)i * CC + lane * 8 + 4));
        float mm[8] = {m0.x, m0.y, m0.z, m0.w, m1.x, m1.y, m1.z, m1.w};
        float dot = a * ql, nn = a * a;
        #pragma unroll
        for (int k = 0; k < 8; ++k) { float f = mm[k]; dot += f * qm[k]; nn += f * f; }
        #pragma unroll
        for (int off = 32; off >= 1; off >>= 1) {
            dot += __shfl_xor(dot, off);
            nn  += __shfl_xor(nn, off);
        }
        float mn = fmaxf(sqrtf(nn), EPSV);
        float s = beta * (dot / (mn * qn)) - gamma * ema[i];
        if (s > m_run) {                  // wave-uniform branch
            float f = expf(m_run - s);    // 0 on first row (exp(-huge))
            float f2 = f * f;
            Z *= f; S2 *= f2; aA *= f;
            #pragma unroll
            for (int k = 0; k < 8; ++k) { a1[k] *= f; a2[k] *= f2; }
            m_run = s;
        }
        float w = expf(s - m_run);
        float w2 = w * w;
        Z += w; S2 += w2; aA += w * a;
        #pragma unroll
        for (int k = 0; k < 8; ++k) { a1[k] += w * mm[k]; a2[k] += w2 * mm[k]; }
    }
    // wave partials -> LDS
    #pragma unroll
    for (int k = 0; k < 8; ++k) {
        lw[wave][lane * 8 + k] = a1[k];
        lw[wave][512 + lane * 8 + k] = a2[k];
    }
    lw[wave][1024 + lane] = aA;
    if (lane == 0) { lw[wave][1088] = m_run; lw[wave][1089] = Z; lw[wave][1090] = S2; }
    __syncthreads();
    // block merge with per-wave rescale
    float mb = lw[0][1088];
    #pragma unroll
    for (int w = 1; w < 8; ++w) mb = fmaxf(mb, lw[w][1088]);
    float fw[8];
    #pragma unroll
    for (int w = 0; w < 8; ++w) fw[w] = expf(lw[w][1088] - mb);
    for (int e = tid; e < 1024; e += 512) {
        float v = 0.f;
        if (e < 512) {
            #pragma unroll
            for (int w = 0; w < 8; ++w) v += fw[w] * lw[w][e];
        } else {
            #pragma unroll
            for (int w = 0; w < 8; ++w) v += fw[w] * fw[w] * lw[w][e];
        }
        pm[(size_t)e * 512 + b] = v;
    }
    if (tid < 64) {
        float v = 0.f;
        #pragma unroll
        for (int w = 0; w < 8; ++w) v += fw[w] * lw[w][1024 + tid];
        pa[tid * 512 + b] = v;
    }
    if (tid == 0) {
        float Zl = 0.f, S2l = 0.f;
        #pragma unroll
        for (int w = 0; w < 8; ++w) {
            Zl  += fw[w] * lw[w][1089];
            S2l += fw[w] * fw[w] * lw[w][1090];
        }
        stats[b] = mb; stats[512 + b] = Zl; stats[1024 + b] = S2l;
    }
}

// ---------------- K5: global stats (was k3g) + reduce partials + epilogue -
// grid 576: every block first recomputes {mx, Zg, S2s} from stats[1536]
// (L2-hot, ~12 shuffles), then block b<64 -> out[b] from pa;
// else c=b-64 -> out[64+c] from pm + dotp/sdot epilogue.
__global__ __launch_bounds__(256) void k5_final(
    const float* __restrict__ ws, const float* __restrict__ pm,
    const float* __restrict__ pa, const float* __restrict__ ber,
    const float* __restrict__ bca, float* __restrict__ out)
{
    __shared__ float red[20];
    const int b = blockIdx.x, tid = threadIdx.x, wave = tid >> 6, lane = tid & 63;
    const float* stats = ws + STOFF;

    float m1 = stats[tid], m2 = stats[256 + tid];
    float mv = fmaxf(m1, m2);
    #pragma unroll
    for (int off = 32; off >= 1; off >>= 1) mv = fmaxf(mv, __shfl_xor(mv, off));
    if (lane == 0) red[wave] = mv;
    __syncthreads();
    const float mx = fmaxf(fmaxf(red[0], red[1]), fmaxf(red[2], red[3]));
    float e1 = expf(m1 - mx), e2 = expf(m2 - mx);
    float zs = e1 * stats[512 + tid]  + e2 * stats[768 + tid];
    float ss = e1 * e1 * stats[1024 + tid] + e2 * e2 * stats[1280 + tid];
    #pragma unroll
    for (int off = 32; off >= 1; off >>= 1) {
        zs += __shfl_xor(zs, off);
        ss += __shfl_xor(ss, off);
    }
    if (lane == 0) { red[4 + wave] = zs; red[8 + wave] = ss; }
    __syncthreads();
    const float Zg  = red[4] + red[5] + red[6] + red[7];
    const float S2s = red[8] + red[9] + red[10] + red[11];
    const float iZ = 1.f / Zg;
    const float sct = e1 * iZ, sct2 = e2 * iZ; // sc1 at tid, tid+256

    if (b < 64) {
        float v = sct * pa[b * 512 + tid] + sct2 * pa[b * 512 + 256 + tid];
        #pragma unroll
        for (int off = 32; off >= 1; off >>= 1) v += __shfl_xor(v, off);
        if (lane == 0) red[12 + wave] = v;
        __syncthreads();
        if (tid == 0) out[b] = red[12] + red[13] + red[14] + red[15];
    } else {
        const int c = b - 64;
        float v1 = sct * pm[(size_t)c * 512 + tid]
                 + sct2 * pm[(size_t)c * 512 + 256 + tid];
        float v2 = sct * sct * pm[(size_t)(512 + c) * 512 + tid]
                 + sct2 * sct2 * pm[(size_t)(512 + c) * 512 + 256 + tid];
        #pragma unroll
        for (int off = 32; off >= 1; off >>= 1) {
            v1 += __shfl_xor(v1, off);
            v2 += __shfl_xor(v2, off);
        }
        if (lane == 0) { red[12 + wave] = v1; red[16 + wave] = v2; }
        __syncthreads();
        if (tid == 0) {
            float s1  = red[12] + red[13] + red[14] + red[15];
            float s2v = red[16] + red[17] + red[18] + red[19];
            float er = ber[c], ch = 0.f, alpha = bca[0];
            #pragma unroll
            for (int p = 0; p < 8; ++p) {
                er    += ws[DOTP + p * 1600 + 576 + c];
                ch    += ws[DOTP + p * 1600 + 1088 + c];
                alpha += ws[SDOT + 16 + p];
            }
            float cx = ws[CONTX + c];
            float S2 = S2s * iZ * iZ;
            float cand = fmaxf(ch + alpha * cx, 0.f);
            out[64 + c] = s1 - er * s2v + S2 * cand;
        }
    }
}

extern "C" void kernel_launch(void* const* d_in, const int* in_sizes, int n_in,
                              void* d_out, int out_size, void* d_ws, size_t ws_size,
                              hipStream_t stream)
{
    const float* h   = (const float*)d_in[0];
    const float* x   = (const float*)d_in[1];
    const float* Mm  = (const float*)d_in[2];
    const float* Ad  = (const float*)d_in[3];
    const float* ema = (const float*)d_in[4];
    const float* Wq  = (const float*)d_in[5];
    const float* bq  = (const float*)d_in[6];
    const float* ush = (const float*)d_in[7];
    const float* bsh = (const float*)d_in[8];
    const float* ulr = (const float*)d_in[9];
    const float* blr = (const float*)d_in[10];
    const float* Wer = (const float*)d_in[11];
    const float* ber = (const float*)d_in[12];
    const float* Wch = (const float*)d_in[13];
    const float* Wci = (const float*)d_in[14];
    const float* uca = (const float*)d_in[15];
    const float* bca = (const float*)d_in[16];

    float* ws    = (float*)d_ws;
    float* stats = ws + STOFF;
    float* pa    = ws + PAOFF;
    float* pm    = ws + PMOFF;
    float* out   = (float*)d_out;

    hipLaunchKernelGGL(k1_gemv,   dim3(1688), dim3(256), 0, stream,
                       h, x, Wq, Wer, Wch, Wci, ush, ulr, uca, ws);
    hipLaunchKernelGGL(k2f_fused, dim3(512),  dim3(512), 0, stream,
                       Mm, Ad, ema, ws, bq, bsh, blr, pm, pa, stats);
    hipLaunchKernelGGL(k5_final,  dim3(576),  dim3(256), 0, stream,
                       ws, pm, pa, ber, bca, out);
}